// Round 4
// baseline (643.685 us; speedup 1.0000x reference)
//
#include <hip/hip_runtime.h>
#include <hip/hip_bf16.h>

typedef __hip_bfloat16 bf16;
typedef short s16x8 __attribute__((ext_vector_type(8)));
typedef float f32x4 __attribute__((ext_vector_type(4)));

#define DIM 2048
#define NHEADS 16
#define NKVH 4
#define HD 128
#define KVDIM 512
#define BSZ 4
#define SEQ 2048
#define MROWS (BSZ*SEQ)
#define NQKV (DIM+2*KVDIM)

// -------- async global->LDS, 16B per lane, wave-uniform LDS base --------
__device__ __forceinline__ void gld_lds16(const bf16* g, short* l) {
  __builtin_amdgcn_global_load_lds((__attribute__((address_space(1))) void*)(void*)g,
                                   (__attribute__((address_space(3))) void*)l, 16, 0, 0);
}

// -------- fp32 -> bf16 cast, 8 elems/thread --------
__global__ __launch_bounds__(256) void cast_bf16(const float* __restrict__ src,
                                                 bf16* __restrict__ dst, int n8) {
  int i = blockIdx.x*256 + threadIdx.x;
  if (i >= n8) return;
  const float4* s4 = (const float4*)src;
  float4 a = s4[2*i];
  float4 b = s4[2*i+1];
  union { bf16 h[8]; uint4 u; } o;
  o.h[0] = __float2bfloat16(a.x); o.h[1] = __float2bfloat16(a.y);
  o.h[2] = __float2bfloat16(a.z); o.h[3] = __float2bfloat16(a.w);
  o.h[4] = __float2bfloat16(b.x); o.h[5] = __float2bfloat16(b.y);
  o.h[6] = __float2bfloat16(b.z); o.h[7] = __float2bfloat16(b.w);
  ((uint4*)dst)[i] = o.u;
}

// -------- merged Wq|Wk|Wv cast into contiguous Wqkv --------
__global__ __launch_bounds__(256) void cast_w3(const float* __restrict__ Wq,
                                               const float* __restrict__ Wk,
                                               const float* __restrict__ Wv,
                                               bf16* __restrict__ dst) {
  int i = blockIdx.x*256 + threadIdx.x;          // 8-elem groups; total 786432
  const float* src; int j;
  if (i < 524288)      { src = Wq; j = i; }
  else if (i < 655360) { src = Wk; j = i - 524288; }
  else                 { src = Wv; j = i - 655360; }
  const float4* s4 = (const float4*)src;
  float4 a = s4[2*j];
  float4 b = s4[2*j+1];
  union { bf16 h[8]; uint4 u; } o;
  o.h[0] = __float2bfloat16(a.x); o.h[1] = __float2bfloat16(a.y);
  o.h[2] = __float2bfloat16(a.z); o.h[3] = __float2bfloat16(a.w);
  o.h[4] = __float2bfloat16(b.x); o.h[5] = __float2bfloat16(b.y);
  o.h[6] = __float2bfloat16(b.z); o.h[7] = __float2bfloat16(b.w);
  ((uint4*)dst)[i] = o.u;
}

// -------- NT GEMM: C[M,N] = A[M,K] @ B[N,K]^T, bf16 in, fp32 acc --------
// EPI=0: plain fp32 C.  EPI=1: scatter bf16 into Q[b,h,s,d]/K[b,h,s,d]/V^T[b,h,d,s].
template<int EPI>
__global__ __launch_bounds__(256) void gemm_nt(
    const bf16* __restrict__ A, const bf16* __restrict__ Bm,
    float* __restrict__ Cf, bf16* __restrict__ Qo, bf16* __restrict__ Ko,
    bf16* __restrict__ Vo, int N, int K) {
  __shared__ short As[128*32] __attribute__((aligned(16)));
  __shared__ short Bs[128*32] __attribute__((aligned(16)));
  const int tid = threadIdx.x;
  const int lane = tid & 63, wid = tid >> 6;
  const int quad = lane >> 4, l15 = lane & 15;
  const int wm = wid >> 1, wn = wid & 1;
  const int m0 = blockIdx.y * 128, n0 = blockIdx.x * 128;

  f32x4 acc[4][4] = {};

  const long aOff = (long)(m0 + wid*32 + (lane>>2)) * K + (lane&3)*8;
  const long bOff = (long)(n0 + wid*32 + (lane>>2)) * K + (lane&3)*8;
  short* ldsA = As + wid*1024;
  short* ldsB = Bs + wid*1024;
  const long rstep = 16L*K;

  for (int k0 = 0; k0 < K; k0 += 32) {
    __syncthreads();
    gld_lds16(A  + aOff + k0,         ldsA);
    gld_lds16(A  + aOff + k0 + rstep, ldsA + 512);
    gld_lds16(Bm + bOff + k0,         ldsB);
    gld_lds16(Bm + bOff + k0 + rstep, ldsB + 512);
    __syncthreads();
    s16x8 af[4], bfr[4];
#pragma unroll
    for (int i = 0; i < 4; i++)
      af[i] = *(const s16x8*)&As[(wm*64 + i*16 + l15)*32 + quad*8];
#pragma unroll
    for (int j = 0; j < 4; j++)
      bfr[j] = *(const s16x8*)&Bs[(wn*64 + j*16 + l15)*32 + quad*8];
#pragma unroll
    for (int i = 0; i < 4; i++)
#pragma unroll
      for (int j = 0; j < 4; j++)
        acc[i][j] = __builtin_amdgcn_mfma_f32_16x16x32_bf16(af[i], bfr[j], acc[i][j], 0, 0, 0);
  }

#pragma unroll
  for (int i = 0; i < 4; i++) {
#pragma unroll
    for (int j = 0; j < 4; j++) {
      const int col = n0 + wn*64 + j*16 + l15;
#pragma unroll
      for (int r = 0; r < 4; r++) {
        const int row = m0 + wm*64 + i*16 + quad*4 + r;
        const float v = acc[i][j][r];
        if (EPI == 0) {
          Cf[(long)row*N + col] = v;
        } else {
          const int b = row >> 11, s = row & (SEQ-1);
          const bf16 hv = __float2bfloat16(v);
          if (col < DIM) {
            const int h = col >> 7, d = col & 127;
            Qo[((long)(b*NHEADS + h)*SEQ + s)*HD + d] = hv;
          } else if (col < DIM + KVDIM) {
            const int c2 = col - DIM, h = c2 >> 7, d = c2 & 127;
            Ko[((long)(b*NKVH + h)*SEQ + s)*HD + d] = hv;
          } else {
            const int c2 = col - DIM - KVDIM, h = c2 >> 7, d = c2 & 127;
            // V stored TRANSPOSED: [b,kvh,d,s]
            Vo[((long)(b*NKVH + h)*HD + d)*SEQ + s] = hv;
          }
        }
      }
    }
  }
}

// -------- RMSNorm + RoPE (+ q_gain * 1/sqrt(HD)) in-place on bf16 [rows][128] --------
__global__ __launch_bounds__(256) void norm_rope(bf16* __restrict__ Qb,
                                                 bf16* __restrict__ Kb,
                                                 const float* __restrict__ gain) {
  const int lane = threadIdx.x & 63, wid = threadIdx.x >> 6;
  const long rid = (long)blockIdx.x*4 + wid;
  const long QR = (long)BSZ*NHEADS*SEQ;
  bf16* ptr; float g; int s;
  if (rid < QR) {
    ptr = Qb + rid*HD;
    s = (int)(rid & (SEQ-1));
    const int h = (int)((rid >> 11) & 15);
    g = gain[h] * 0.08838834764831845f;   // fold softmax scale 1/sqrt(128) into q
  } else {
    const long r2 = rid - QR;
    ptr = Kb + r2*HD;
    s = (int)(r2 & (SEQ-1));
    g = 1.0f;
  }
  float x1 = __bfloat162float(ptr[lane]);
  float x2 = __bfloat162float(ptr[lane+64]);
  float ss = x1*x1 + x2*x2;
#pragma unroll
  for (int off = 1; off < 64; off <<= 1) ss += __shfl_xor(ss, off);
  const float rn = rsqrtf(ss*(1.0f/128.0f) + 1.1920928955078125e-07f);
  const float inv_freq = exp2f((float)lane * -0.20762050593046014f);
  float sn, cs;
  sincosf((float)s * inv_freq, &sn, &cs);
  const float q1 = x1*rn, q2 = x2*rn;
  ptr[lane]    = __float2bfloat16((q1*cs + q2*sn)*g);
  ptr[lane+64] = __float2bfloat16((q2*cs - q1*sn)*g);
}

// -------- causal flash attention: S^T form, fixed-shift softmax, qt-paired --------
// Block x handles query-tiles qt=15-x (heavy) then qt=x (light): (32-2x)+(2x+2)=34
// tiles for EVERY block -> perfect balance. Grid 8x64 = 512 blocks = 2/CU, one round.
// K/V tile kt+1 prefetched into registers during tile kt's compute (hides HBM/L2
// latency); vmcnt drain lands at next iteration's ds_write, not in the serial chain.
__global__ __launch_bounds__(256, 2) void attn(
    const bf16* __restrict__ Qb, const bf16* __restrict__ Kb,
    const bf16* __restrict__ Vtg, bf16* __restrict__ Yb) {
  __shared__ short Kt[64*136]  __attribute__((aligned(16)));  // [key][k] pad->136
  __shared__ short Vt[128*72]  __attribute__((aligned(16)));  // [d][key] pad->72
  __shared__ short Pt[4*2304]  __attribute__((aligned(16)));  // per-wave, per-group [16 q][72]

  const int tid = threadIdx.x;
  const int lane = tid & 63, wid = tid >> 6;
  const int quad = lane >> 4, l15 = lane & 15;
  const int xb = blockIdx.x;                    // 0..7
  const int bh = blockIdx.y;
  const int b = bh >> 4, h = bh & 15, kvh = h >> 2;

  const bf16* kbase = Kb  + (long)(b*NKVH + kvh)*SEQ*HD;
  const bf16* vbase = Vtg + (long)(b*NKVH + kvh)*HD*SEQ;   // [d][s]
  short* pw0 = Pt + wid*2304;
  short* pw1 = pw0 + 1152;
  const int krow = tid >> 4, kc = (tid & 15)*8;
  const int vrow = tid >> 3, vc = (tid & 7)*8;

  for (int phase = 0; phase < 2; phase++) {
    const int qt = phase ? xb : (15 - xb);      // heavy first
    const int q0 = qt*128 + wid*16 + l15;       // group 0 query
    const int q1 = q0 + 64;                     // group 1 query
    const bf16* qr0 = Qb + ((long)(b*NHEADS + h)*SEQ + q0)*HD + quad*8;
    s16x8 qa0[4], qa1[4];
#pragma unroll
    for (int st = 0; st < 4; st++) {
      qa0[st] = *(const s16x8*)(qr0 + st*32);
      qa1[st] = *(const s16x8*)(qr0 + 64*HD + st*32);
    }

    f32x4 o0[8] = {}, o1[8] = {};
    float li0 = 0.0f, li1 = 0.0f;
    const int ktiles = 2*qt + 2;

    // preload tile 0 into registers
    uint4 kreg[4], vreg[4];
#pragma unroll
    for (int i = 0; i < 4; i++)
      kreg[i] = *(const uint4*)(kbase + (long)(i*16 + krow)*HD + kc);
#pragma unroll
    for (int i = 0; i < 4; i++)
      vreg[i] = *(const uint4*)(vbase + (long)(i*32 + vrow)*SEQ + vc);

    for (int kt = 0; kt < ktiles; kt++) {
      __syncthreads();
#pragma unroll
      for (int i = 0; i < 4; i++)
        *(uint4*)&Kt[(i*16 + krow)*136 + kc] = kreg[i];
#pragma unroll
      for (int i = 0; i < 4; i++)
        *(uint4*)&Vt[(i*32 + vrow)*72 + vc] = vreg[i];
      __syncthreads();

      // prefetch next tile (in flight through the whole compute below)
      if (kt + 1 < ktiles) {
#pragma unroll
        for (int i = 0; i < 4; i++)
          kreg[i] = *(const uint4*)(kbase + (long)((kt+1)*64 + i*16 + krow)*HD + kc);
#pragma unroll
        for (int i = 0; i < 4; i++)
          vreg[i] = *(const uint4*)(vbase + (long)(i*32 + vrow)*SEQ + (kt+1)*64 + vc);
      }

      // S^T = K Q^T for both groups; kf frags shared
      f32x4 s0[4] = {}, s1[4] = {};
#pragma unroll
      for (int nt = 0; nt < 4; nt++) {
        s16x8 kf[4];
#pragma unroll
        for (int st = 0; st < 4; st++)
          kf[st] = *(const s16x8*)&Kt[(nt*16 + l15)*136 + st*32 + quad*8];
#pragma unroll
        for (int st = 0; st < 4; st++) {
          s0[nt] = __builtin_amdgcn_mfma_f32_16x16x32_bf16(kf[st], qa0[st], s0[nt], 0, 0, 0);
          s1[nt] = __builtin_amdgcn_mfma_f32_16x16x32_bf16(kf[st], qa1[st], s1[nt], 0, 0, 0);
        }
      }

      // fixed-shift softmax: P = exp(s - 12); |s|<11.5 provably (rms-normed q,k)
      const bool d0 = (kt >= 2*qt);
      const bool d1 = (kt >  2*qt);
      const int tb = kt*64 + quad*4;
      union { bf16 h[16]; unsigned long long u[4]; } p0, p1;
      float rs0 = 0.0f, rs1 = 0.0f;
#pragma unroll
      for (int nt = 0; nt < 4; nt++) {
#pragma unroll
        for (int r = 0; r < 4; r++) {
          const int t = tb + nt*16 + r;
          float v0 = s0[nt][r], v1 = s1[nt][r];
          if (d0 && (t > q0)) v0 = -1e30f;
          if (d1 && (t > q1)) v1 = -1e30f;
          const float e0 = __expf(v0 - 12.0f);
          const float e1 = __expf(v1 - 12.0f);
          rs0 += e0; rs1 += e1;
          p0.h[nt*4+r] = __float2bfloat16(e0);
          p1.h[nt*4+r] = __float2bfloat16(e1);
        }
      }
      li0 += rs0; li1 += rs1;
#pragma unroll
      for (int nt = 0; nt < 4; nt++) {
        *(unsigned long long*)&pw0[l15*72 + nt*16 + quad*4] = p0.u[nt];
        *(unsigned long long*)&pw1[l15*72 + nt*16 + quad*4] = p1.u[nt];
      }

      // O^T += V^T P^T for both groups; vf frags shared
#pragma unroll
      for (int st = 0; st < 2; st++) {
        s16x8 pf0 = *(const s16x8*)&pw0[l15*72 + st*32 + quad*8];
        s16x8 pf1 = *(const s16x8*)&pw1[l15*72 + st*32 + quad*8];
#pragma unroll
        for (int dt = 0; dt < 8; dt++) {
          s16x8 vf = *(const s16x8*)&Vt[(dt*16 + l15)*72 + st*32 + quad*8];
          o0[dt] = __builtin_amdgcn_mfma_f32_16x16x32_bf16(vf, pf0, o0[dt], 0, 0, 0);
          o1[dt] = __builtin_amdgcn_mfma_f32_16x16x32_bf16(vf, pf1, o1[dt], 0, 0, 0);
        }
      }
    }

    // finalize li (once per phase), then transpose O^T -> O via wave-private Pt slice
    li0 += __shfl_xor(li0, 16); li0 += __shfl_xor(li0, 32);
    li1 += __shfl_xor(li1, 16); li1 += __shfl_xor(li1, 32);
    const float inv0 = 1.0f / li0, inv1 = 1.0f / li1;

    short* ep = pw0;
#pragma unroll
    for (int g = 0; g < 2; g++) {
      const float inv = g ? inv1 : inv0;
      const f32x4* o = g ? o1 : o0;
      const int qg = g ? q1 : q0;
#pragma unroll
      for (int dt = 0; dt < 8; dt++) {
        union { bf16 h[4]; unsigned long long u; } pk;
        pk.h[0] = __float2bfloat16(o[dt][0]*inv);
        pk.h[1] = __float2bfloat16(o[dt][1]*inv);
        pk.h[2] = __float2bfloat16(o[dt][2]*inv);
        pk.h[3] = __float2bfloat16(o[dt][3]*inv);
        *(unsigned long long*)&ep[l15*136 + dt*16 + quad*4] = pk.u;
      }
      bf16* yb = Yb + ((long)(b*SEQ + qg - l15))*DIM + h*HD;
#pragma unroll
      for (int p = 0; p < 4; p++) {
        const int c = quad + 4*p;
        uint4 yv = *(const uint4*)&ep[l15*136 + c*8];
        *(uint4*)&yb[(long)l15*DIM + c*8] = yv;
      }
    }
  }
}

extern "C" void kernel_launch(void* const* d_in, const int* in_sizes, int n_in,
                              void* d_out, int out_size, void* d_ws, size_t ws_size,
                              hipStream_t stream) {
  (void)in_sizes; (void)n_in; (void)out_size; (void)ws_size;
  const float* x   = (const float*)d_in[0];
  const float* Wq  = (const float*)d_in[1];
  const float* Wk  = (const float*)d_in[2];
  const float* Wv  = (const float*)d_in[3];
  const float* Wo  = (const float*)d_in[4];
  const float* qg  = (const float*)d_in[5];

  char* ws = (char*)d_ws;
  bf16* xbf  = (bf16*)(ws);                         // 32 MB
  bf16* Wqkv = (bf16*)(ws + 33554432);              // 12 MB
  bf16* Wob  = (bf16*)(ws + 46137344);              //  8 MB
  bf16* Qb   = (bf16*)(ws + 54525952);              // 32 MB
  bf16* Kb   = (bf16*)(ws + 88080384);              //  8 MB
  bf16* Vb   = (bf16*)(ws + 96468992);              //  8 MB (transposed [b,kvh,d,s])
  bf16* Yb   = (bf16*)(ws + 104857600);             // 32 MB

  cast_bf16<<<8192, 256, 0, stream>>>(x,  xbf, MROWS*DIM/8);
  cast_w3<<<3072, 256, 0, stream>>>(Wq, Wk, Wv, Wqkv);
  cast_bf16<<<2048, 256, 0, stream>>>(Wo, Wob, DIM*DIM/8);

  gemm_nt<1><<<dim3(NQKV/128, MROWS/128), 256, 0, stream>>>(
      xbf, Wqkv, nullptr, Qb, Kb, Vb, NQKV, DIM);

  norm_rope<<<40960, 256, 0, stream>>>(Qb, Kb, qg);

  attn<<<dim3(8, BSZ*NHEADS), 256, 0, stream>>>(Qb, Kb, Vb, Yb);

  gemm_nt<0><<<dim3(DIM/128, MROWS/128), 256, 0, stream>>>(
      Yb, Wob, (float*)d_out, nullptr, nullptr, nullptr, DIM, DIM);
}

// Round 5
// 515.946 us; speedup vs baseline: 1.2476x; 1.2476x over previous
//
#include <hip/hip_runtime.h>
#include <hip/hip_bf16.h>

typedef __hip_bfloat16 bf16;
typedef short s16x8 __attribute__((ext_vector_type(8)));
typedef float f32x4 __attribute__((ext_vector_type(4)));

#define DIM 2048
#define NHEADS 16
#define NKVH 4
#define HD 128
#define KVDIM 512
#define BSZ 4
#define SEQ 2048
#define MROWS (BSZ*SEQ)
#define NQKV (DIM+2*KVDIM)

// -------- async global->LDS, 16B per lane, wave-uniform LDS base --------
__device__ __forceinline__ void gld_lds16(const bf16* g, short* l) {
  __builtin_amdgcn_global_load_lds((__attribute__((address_space(1))) void*)(void*)g,
                                   (__attribute__((address_space(3))) void*)l, 16, 0, 0);
}

// -------- fp32 -> bf16 cast, 8 elems/thread --------
__global__ __launch_bounds__(256) void cast_bf16(const float* __restrict__ src,
                                                 bf16* __restrict__ dst, int n8) {
  int i = blockIdx.x*256 + threadIdx.x;
  if (i >= n8) return;
  const float4* s4 = (const float4*)src;
  float4 a = s4[2*i];
  float4 b = s4[2*i+1];
  union { bf16 h[8]; uint4 u; } o;
  o.h[0] = __float2bfloat16(a.x); o.h[1] = __float2bfloat16(a.y);
  o.h[2] = __float2bfloat16(a.z); o.h[3] = __float2bfloat16(a.w);
  o.h[4] = __float2bfloat16(b.x); o.h[5] = __float2bfloat16(b.y);
  o.h[6] = __float2bfloat16(b.z); o.h[7] = __float2bfloat16(b.w);
  ((uint4*)dst)[i] = o.u;
}

// -------- merged Wq|Wk|Wv cast into contiguous Wqkv --------
__global__ __launch_bounds__(256) void cast_w3(const float* __restrict__ Wq,
                                               const float* __restrict__ Wk,
                                               const float* __restrict__ Wv,
                                               bf16* __restrict__ dst) {
  int i = blockIdx.x*256 + threadIdx.x;          // 8-elem groups; total 786432
  const float* src; int j;
  if (i < 524288)      { src = Wq; j = i; }
  else if (i < 655360) { src = Wk; j = i - 524288; }
  else                 { src = Wv; j = i - 655360; }
  const float4* s4 = (const float4*)src;
  float4 a = s4[2*j];
  float4 b = s4[2*j+1];
  union { bf16 h[8]; uint4 u; } o;
  o.h[0] = __float2bfloat16(a.x); o.h[1] = __float2bfloat16(a.y);
  o.h[2] = __float2bfloat16(a.z); o.h[3] = __float2bfloat16(a.w);
  o.h[4] = __float2bfloat16(b.x); o.h[5] = __float2bfloat16(b.y);
  o.h[6] = __float2bfloat16(b.z); o.h[7] = __float2bfloat16(b.w);
  ((uint4*)dst)[i] = o.u;
}

// -------- NT GEMM: C[M,N] = A[M,K] @ B[N,K]^T, bf16 in, fp32 acc --------
// EPI=0: plain fp32 C.  EPI=1: scatter bf16 into Q[b,h,s,d]/K[b,h,s,d]/V^T[b,h,d,s].
template<int EPI>
__global__ __launch_bounds__(256) void gemm_nt(
    const bf16* __restrict__ A, const bf16* __restrict__ Bm,
    float* __restrict__ Cf, bf16* __restrict__ Qo, bf16* __restrict__ Ko,
    bf16* __restrict__ Vo, int N, int K) {
  __shared__ short As[128*32] __attribute__((aligned(16)));
  __shared__ short Bs[128*32] __attribute__((aligned(16)));
  const int tid = threadIdx.x;
  const int lane = tid & 63, wid = tid >> 6;
  const int quad = lane >> 4, l15 = lane & 15;
  const int wm = wid >> 1, wn = wid & 1;
  const int m0 = blockIdx.y * 128, n0 = blockIdx.x * 128;

  f32x4 acc[4][4] = {};

  const long aOff = (long)(m0 + wid*32 + (lane>>2)) * K + (lane&3)*8;
  const long bOff = (long)(n0 + wid*32 + (lane>>2)) * K + (lane&3)*8;
  short* ldsA = As + wid*1024;
  short* ldsB = Bs + wid*1024;
  const long rstep = 16L*K;

  for (int k0 = 0; k0 < K; k0 += 32) {
    __syncthreads();
    gld_lds16(A  + aOff + k0,         ldsA);
    gld_lds16(A  + aOff + k0 + rstep, ldsA + 512);
    gld_lds16(Bm + bOff + k0,         ldsB);
    gld_lds16(Bm + bOff + k0 + rstep, ldsB + 512);
    __syncthreads();
    s16x8 af[4], bfr[4];
#pragma unroll
    for (int i = 0; i < 4; i++)
      af[i] = *(const s16x8*)&As[(wm*64 + i*16 + l15)*32 + quad*8];
#pragma unroll
    for (int j = 0; j < 4; j++)
      bfr[j] = *(const s16x8*)&Bs[(wn*64 + j*16 + l15)*32 + quad*8];
#pragma unroll
    for (int i = 0; i < 4; i++)
#pragma unroll
      for (int j = 0; j < 4; j++)
        acc[i][j] = __builtin_amdgcn_mfma_f32_16x16x32_bf16(af[i], bfr[j], acc[i][j], 0, 0, 0);
  }

#pragma unroll
  for (int i = 0; i < 4; i++) {
#pragma unroll
    for (int j = 0; j < 4; j++) {
      const int col = n0 + wn*64 + j*16 + l15;
#pragma unroll
      for (int r = 0; r < 4; r++) {
        const int row = m0 + wm*64 + i*16 + quad*4 + r;
        const float v = acc[i][j][r];
        if (EPI == 0) {
          Cf[(long)row*N + col] = v;
        } else {
          const int b = row >> 11, s = row & (SEQ-1);
          const bf16 hv = __float2bfloat16(v);
          if (col < DIM) {
            const int h = col >> 7, d = col & 127;
            Qo[((long)(b*NHEADS + h)*SEQ + s)*HD + d] = hv;
          } else if (col < DIM + KVDIM) {
            const int c2 = col - DIM, h = c2 >> 7, d = c2 & 127;
            Ko[((long)(b*NKVH + h)*SEQ + s)*HD + d] = hv;
          } else {
            const int c2 = col - DIM - KVDIM, h = c2 >> 7, d = c2 & 127;
            // V stored TRANSPOSED: [b,kvh,d,s]
            Vo[((long)(b*NKVH + h)*HD + d)*SEQ + s] = hv;
          }
        }
      }
    }
  }
}

// -------- RMSNorm + RoPE (+ q_gain * 1/sqrt(HD)) in-place on bf16 [rows][128] --------
__global__ __launch_bounds__(256) void norm_rope(bf16* __restrict__ Qb,
                                                 bf16* __restrict__ Kb,
                                                 const float* __restrict__ gain) {
  const int lane = threadIdx.x & 63, wid = threadIdx.x >> 6;
  const long rid = (long)blockIdx.x*4 + wid;
  const long QR = (long)BSZ*NHEADS*SEQ;
  bf16* ptr; float g; int s;
  if (rid < QR) {
    ptr = Qb + rid*HD;
    s = (int)(rid & (SEQ-1));
    const int h = (int)((rid >> 11) & 15);
    g = gain[h] * 0.08838834764831845f;   // fold softmax scale 1/sqrt(128) into q
  } else {
    const long r2 = rid - QR;
    ptr = Kb + r2*HD;
    s = (int)(r2 & (SEQ-1));
    g = 1.0f;
  }
  float x1 = __bfloat162float(ptr[lane]);
  float x2 = __bfloat162float(ptr[lane+64]);
  float ss = x1*x1 + x2*x2;
#pragma unroll
  for (int off = 1; off < 64; off <<= 1) ss += __shfl_xor(ss, off);
  const float rn = rsqrtf(ss*(1.0f/128.0f) + 1.1920928955078125e-07f);
  const float inv_freq = exp2f((float)lane * -0.20762050593046014f);
  float sn, cs;
  sincosf((float)s * inv_freq, &sn, &cs);
  const float q1 = x1*rn, q2 = x2*rn;
  ptr[lane]    = __float2bfloat16((q1*cs + q2*sn)*g);
  ptr[lane+64] = __float2bfloat16((q2*cs - q1*sn)*g);
}

// -------- causal flash attention: S^T form, fixed-shift softmax, qt-paired --------
// Block x handles query-tiles qt=15-x then qt=x: 34 key-tiles for EVERY block ->
// perfect balance, grid 8x64=512 blocks = exactly 2/CU, one dispatch round.
// NOTE round-4 lesson: register K/V prefetch spilled to scratch (WRITE_SIZE 32->456MB,
// 237us). Staging stays as plain in-loop global->VGPR->ds_write (108-reg allocation).
__global__ __launch_bounds__(256, 2) void attn(
    const bf16* __restrict__ Qb, const bf16* __restrict__ Kb,
    const bf16* __restrict__ Vtg, bf16* __restrict__ Yb) {
  __shared__ short Kt[64*136]  __attribute__((aligned(16)));  // [key][k] pad->136
  __shared__ short Vt[128*72]  __attribute__((aligned(16)));  // [d][key] pad->72
  __shared__ short Pt[4*2304]  __attribute__((aligned(16)));  // per-wave, per-group [16 q][72]

  const int tid = threadIdx.x;
  const int lane = tid & 63, wid = tid >> 6;
  const int quad = lane >> 4, l15 = lane & 15;
  const int xb = blockIdx.x;                    // 0..7
  const int bh = blockIdx.y;
  const int b = bh >> 4, h = bh & 15, kvh = h >> 2;

  const bf16* kbase = Kb  + (long)(b*NKVH + kvh)*SEQ*HD;
  const bf16* vbase = Vtg + (long)(b*NKVH + kvh)*HD*SEQ;   // [d][s]
  short* pw0 = Pt + wid*2304;
  short* pw1 = pw0 + 1152;
  const int krow = tid >> 4, kc = (tid & 15)*8;
  const int vrow = tid >> 3, vc = (tid & 7)*8;

  for (int phase = 0; phase < 2; phase++) {
    const int qt = phase ? xb : (15 - xb);      // heavy first
    const int q0 = qt*128 + wid*16 + l15;       // group 0 query
    const int q1 = q0 + 64;                     // group 1 query
    const bf16* qr0 = Qb + ((long)(b*NHEADS + h)*SEQ + q0)*HD + quad*8;
    s16x8 qa0[4], qa1[4];
#pragma unroll
    for (int st = 0; st < 4; st++) {
      qa0[st] = *(const s16x8*)(qr0 + st*32);
      qa1[st] = *(const s16x8*)(qr0 + 64*HD + st*32);
    }

    f32x4 o0[8] = {}, o1[8] = {};
    float li0 = 0.0f, li1 = 0.0f;
    const int ktiles = 2*qt + 2;

    for (int kt = 0; kt < ktiles; kt++) {
      __syncthreads();
      // stage K tile [64][128] and V^T tile [128][64] (vectorized, conflict-audited)
#pragma unroll
      for (int i = 0; i < 4; i++) {
        uint4 kv = *(const uint4*)(kbase + (long)(kt*64 + i*16 + krow)*HD + kc);
        *(uint4*)&Kt[(i*16 + krow)*136 + kc] = kv;
      }
#pragma unroll
      for (int i = 0; i < 4; i++) {
        uint4 vv = *(const uint4*)(vbase + (long)(i*32 + vrow)*SEQ + kt*64 + vc);
        *(uint4*)&Vt[(i*32 + vrow)*72 + vc] = vv;
      }
      __syncthreads();

      // S^T = K Q^T for both groups; kf frags shared
      f32x4 s0[4] = {}, s1[4] = {};
#pragma unroll
      for (int nt = 0; nt < 4; nt++) {
        s16x8 kf[4];
#pragma unroll
        for (int st = 0; st < 4; st++)
          kf[st] = *(const s16x8*)&Kt[(nt*16 + l15)*136 + st*32 + quad*8];
#pragma unroll
        for (int st = 0; st < 4; st++) {
          s0[nt] = __builtin_amdgcn_mfma_f32_16x16x32_bf16(kf[st], qa0[st], s0[nt], 0, 0, 0);
          s1[nt] = __builtin_amdgcn_mfma_f32_16x16x32_bf16(kf[st], qa1[st], s1[nt], 0, 0, 0);
        }
      }

      // fixed-shift softmax: P = exp(s - 12); |s|<11.5 provably (rms-normed q,k)
      const bool d0 = (kt >= 2*qt);
      const bool d1 = (kt >  2*qt);
      const int tb = kt*64 + quad*4;
      union { bf16 h[16]; unsigned long long u[4]; } p0, p1;
      float rs0 = 0.0f, rs1 = 0.0f;
#pragma unroll
      for (int nt = 0; nt < 4; nt++) {
#pragma unroll
        for (int r = 0; r < 4; r++) {
          const int t = tb + nt*16 + r;
          float v0 = s0[nt][r], v1 = s1[nt][r];
          if (d0 && (t > q0)) v0 = -1e30f;
          if (d1 && (t > q1)) v1 = -1e30f;
          const float e0 = __expf(v0 - 12.0f);
          const float e1 = __expf(v1 - 12.0f);
          rs0 += e0; rs1 += e1;
          p0.h[nt*4+r] = __float2bfloat16(e0);
          p1.h[nt*4+r] = __float2bfloat16(e1);
        }
      }
      li0 += rs0; li1 += rs1;
#pragma unroll
      for (int nt = 0; nt < 4; nt++) {
        *(unsigned long long*)&pw0[l15*72 + nt*16 + quad*4] = p0.u[nt];
        *(unsigned long long*)&pw1[l15*72 + nt*16 + quad*4] = p1.u[nt];
      }

      // O^T += V^T P^T for both groups; vf frags shared
#pragma unroll
      for (int st = 0; st < 2; st++) {
        s16x8 pf0 = *(const s16x8*)&pw0[l15*72 + st*32 + quad*8];
        s16x8 pf1 = *(const s16x8*)&pw1[l15*72 + st*32 + quad*8];
#pragma unroll
        for (int dt = 0; dt < 8; dt++) {
          s16x8 vf = *(const s16x8*)&Vt[(dt*16 + l15)*72 + st*32 + quad*8];
          o0[dt] = __builtin_amdgcn_mfma_f32_16x16x32_bf16(vf, pf0, o0[dt], 0, 0, 0);
          o1[dt] = __builtin_amdgcn_mfma_f32_16x16x32_bf16(vf, pf1, o1[dt], 0, 0, 0);
        }
      }
    }

    // finalize li (once per phase), then transpose O^T -> O via wave-private Pt slice
    li0 += __shfl_xor(li0, 16); li0 += __shfl_xor(li0, 32);
    li1 += __shfl_xor(li1, 16); li1 += __shfl_xor(li1, 32);
    const float inv0 = 1.0f / li0, inv1 = 1.0f / li1;

    short* ep = pw0;
#pragma unroll
    for (int g = 0; g < 2; g++) {
      const float inv = g ? inv1 : inv0;
      const f32x4* o = g ? o1 : o0;
      const int qg = g ? q1 : q0;
#pragma unroll
      for (int dt = 0; dt < 8; dt++) {
        union { bf16 h[4]; unsigned long long u; } pk;
        pk.h[0] = __float2bfloat16(o[dt][0]*inv);
        pk.h[1] = __float2bfloat16(o[dt][1]*inv);
        pk.h[2] = __float2bfloat16(o[dt][2]*inv);
        pk.h[3] = __float2bfloat16(o[dt][3]*inv);
        *(unsigned long long*)&ep[l15*136 + dt*16 + quad*4] = pk.u;
      }
      bf16* yb = Yb + ((long)(b*SEQ + qg - l15))*DIM + h*HD;
#pragma unroll
      for (int p = 0; p < 4; p++) {
        const int c = quad + 4*p;
        uint4 yv = *(const uint4*)&ep[l15*136 + c*8];
        *(uint4*)&yb[(long)l15*DIM + c*8] = yv;
      }
    }
  }
}

extern "C" void kernel_launch(void* const* d_in, const int* in_sizes, int n_in,
                              void* d_out, int out_size, void* d_ws, size_t ws_size,
                              hipStream_t stream) {
  (void)in_sizes; (void)n_in; (void)out_size; (void)ws_size;
  const float* x   = (const float*)d_in[0];
  const float* Wq  = (const float*)d_in[1];
  const float* Wk  = (const float*)d_in[2];
  const float* Wv  = (const float*)d_in[3];
  const float* Wo  = (const float*)d_in[4];
  const float* qg  = (const float*)d_in[5];

  char* ws = (char*)d_ws;
  bf16* xbf  = (bf16*)(ws);                         // 32 MB
  bf16* Wqkv = (bf16*)(ws + 33554432);              // 12 MB
  bf16* Wob  = (bf16*)(ws + 46137344);              //  8 MB
  bf16* Qb   = (bf16*)(ws + 54525952);              // 32 MB
  bf16* Kb   = (bf16*)(ws + 88080384);              //  8 MB
  bf16* Vb   = (bf16*)(ws + 96468992);              //  8 MB (transposed [b,kvh,d,s])
  bf16* Yb   = (bf16*)(ws + 104857600);             // 32 MB

  cast_bf16<<<8192, 256, 0, stream>>>(x,  xbf, MROWS*DIM/8);
  cast_w3<<<3072, 256, 0, stream>>>(Wq, Wk, Wv, Wqkv);
  cast_bf16<<<2048, 256, 0, stream>>>(Wo, Wob, DIM*DIM/8);

  gemm_nt<1><<<dim3(NQKV/128, MROWS/128), 256, 0, stream>>>(
      xbf, Wqkv, nullptr, Qb, Kb, Vb, NQKV, DIM);

  norm_rope<<<40960, 256, 0, stream>>>(Qb, Kb, qg);

  attn<<<dim3(8, BSZ*NHEADS), 256, 0, stream>>>(Qb, Kb, Vb, Yb);

  gemm_nt<0><<<dim3(DIM/128, MROWS/128), 256, 0, stream>>>(
      Yb, Wob, (float*)d_out, nullptr, nullptr, nullptr, DIM, DIM);
}